// Round 2
// baseline (133.871 us; speedup 1.0000x reference)
//
#include <hip/hip_runtime.h>
#include <hip/hip_bf16.h>

typedef short v8s __attribute__((ext_vector_type(8)));
typedef float v4f __attribute__((ext_vector_type(4)));

#define NB 4
#define NC 32
#define NT 1024
#define NU 32
#define NH 128

static __device__ __forceinline__ unsigned short f2bf(float f) {
    unsigned int u = __float_as_uint(f);
    return (unsigned short)((u + 0x7fffu + ((u >> 16) & 1u)) >> 16);  // RNE
}

// ---------------- Kernel A: q/k projections + bf16 copies ----------------
__global__ __launch_bounds__(256) void prep_kernel(
    const float* __restrict__ x, const float* __restrict__ Wt,
    const float* __restrict__ Wx, const float* __restrict__ bh,
    const float* __restrict__ W1, const float* __restrict__ W2,
    float* __restrict__ qb, float* __restrict__ kx,
    unsigned short* __restrict__ xbf,
    unsigned short* __restrict__ w1bf, unsigned short* __restrict__ w2bf)
{
    int bid = blockIdx.x, tid = threadIdx.x;
    if (bid < 512) {
        int gid = (bid << 8) + tid;
        int row = gid >> 5, u = gid & 31;        // row = b*1024 + t
        int b = row >> 10, t = row & 1023;
        const float* xp = x + (size_t)b * (NC * NT) + t;
        float aq = 0.f, ak = 0.f;
        #pragma unroll
        for (int c = 0; c < NC; ++c) {
            float xv = xp[c * NT];
            aq = fmaf(xv, Wt[c * NU + u], aq);
            ak = fmaf(xv, Wx[c * NU + u], ak);
        }
        qb[(size_t)row * NU + u] = aq + bh[u];   // q + bh folded
        kx[(size_t)row * NU + u] = ak;
    } else if (bid < 640) {                      // x -> bf16, same [b][c][t] layout
        int base = ((bid - 512) << 10) + (tid << 2);
        float4 xv = *(const float4*)(x + base);
        xbf[base]     = f2bf(xv.x);
        xbf[base + 1] = f2bf(xv.y);
        xbf[base + 2] = f2bf(xv.z);
        xbf[base + 3] = f2bf(xv.w);
    } else if (bid < 642) {                      // W1 (128x32) -> bf16
        int base = ((bid - 640) << 11) + (tid << 3);
        #pragma unroll
        for (int i = 0; i < 8; ++i) w1bf[base + i] = f2bf(W1[base + i]);
    } else {                                     // W2 (32x128) -> bf16
        int base = ((bid - 642) << 11) + (tid << 3);
        #pragma unroll
        for (int i = 0; i < 8; ++i) w2bf[base + i] = f2bf(W2[base + i]);
    }
}

// ---------------- Kernel B: e = Wa . tanh(q+k+bh) + ba, softmax, write a (f32) ----------------
// 1 wave handles 2 rows (i-values); lane l handles j = m*64 + l for m in [0,16)
__global__ __launch_bounds__(256) void attn_kernel(
    const float* __restrict__ qb, const float* __restrict__ kx,
    const float* __restrict__ Wa, const float* __restrict__ ba,
    float* __restrict__ a_out)
{
    const int lane = threadIdx.x & 63;
    const int wv = threadIdx.x >> 6;
    const int row0 = (blockIdx.x << 3) + (wv << 1);
    const int b = row0 >> 10;

    float wa[NU];                                 // uniform -> scalar loads
    #pragma unroll
    for (int u = 0; u < NU; ++u) wa[u] = Wa[u];
    const float bav = ba[0];

    float q0[NU], q1[NU];
    {
        const float* qp = qb + (size_t)row0 * NU;
        #pragma unroll
        for (int u = 0; u < NU; u += 4) {
            float4 t4 = *(const float4*)(qp + u);
            q0[u] = t4.x; q0[u + 1] = t4.y; q0[u + 2] = t4.z; q0[u + 3] = t4.w;
        }
        #pragma unroll
        for (int u = 0; u < NU; u += 4) {
            float4 t4 = *(const float4*)(qp + NU + u);
            q1[u] = t4.x; q1[u + 1] = t4.y; q1[u + 2] = t4.z; q1[u + 3] = t4.w;
        }
    }

    // tanh(z) ~= z + z*z2*(C1 + C2 z2 + C3 z2^2 + C4 z2^3); |z| <= ~0.7 here
    const float C1 = -0.33333334f, C2 = 0.13333334f, C3 = -0.05396825f, C4 = 0.021869488f;

    float e0[16], e1[16];
    const float* kbp = kx + ((size_t)(b << 10)) * NU;
    #pragma unroll
    for (int m = 0; m < 16; ++m) {
        const float* kp = kbp + (size_t)((m << 6) + lane) * NU;
        float kr[NU];
        #pragma unroll
        for (int u = 0; u < NU; u += 4) {
            float4 t4 = *(const float4*)(kp + u);
            kr[u] = t4.x; kr[u + 1] = t4.y; kr[u + 2] = t4.z; kr[u + 3] = t4.w;
        }
        float a0 = 0.f, a1 = 0.f;
        #pragma unroll
        for (int u = 0; u < NU; ++u) {
            float z0 = q0[u] + kr[u];
            float z1 = q1[u] + kr[u];
            float s0 = z0 * z0, s1 = z1 * z1;
            float p0 = fmaf(s0, C4, C3), p1 = fmaf(s1, C4, C3);
            p0 = fmaf(s0, p0, C2);  p1 = fmaf(s1, p1, C2);
            p0 = fmaf(s0, p0, C1);  p1 = fmaf(s1, p1, C1);
            float t0 = fmaf(z0 * s0, p0, z0);
            float t1 = fmaf(z1 * s1, p1, z1);
            a0 = fmaf(wa[u], t0, a0);
            a1 = fmaf(wa[u], t1, a1);
        }
        e0[m] = a0 + bav;
        e1[m] = a1 + bav;
    }

    // exact reference semantics: shift by row max, denom = sum + 1e-5
    float mx0 = e0[0], mx1 = e1[0];
    #pragma unroll
    for (int m = 1; m < 16; ++m) { mx0 = fmaxf(mx0, e0[m]); mx1 = fmaxf(mx1, e1[m]); }
    #pragma unroll
    for (int o = 32; o; o >>= 1) {
        mx0 = fmaxf(mx0, __shfl_xor(mx0, o));
        mx1 = fmaxf(mx1, __shfl_xor(mx1, o));
    }
    float S0 = 0.f, S1 = 0.f;
    float s0a[16], s1a[16];
    #pragma unroll
    for (int m = 0; m < 16; ++m) {
        s0a[m] = __expf(e0[m] - mx0); S0 += s0a[m];
        s1a[m] = __expf(e1[m] - mx1); S1 += s1a[m];
    }
    #pragma unroll
    for (int o = 32; o; o >>= 1) { S0 += __shfl_xor(S0, o); S1 += __shfl_xor(S1, o); }
    float i0 = 1.f / (S0 + 1e-5f);
    float i1 = 1.f / (S1 + 1e-5f);

    float* a0p = a_out + ((size_t)row0 << 10) + lane;
    #pragma unroll
    for (int m = 0; m < 16; ++m) {
        a0p[(m << 6)]      = s0a[m] * i0;
        a0p[NT + (m << 6)] = s1a[m] * i1;
    }
}

// ---------------- Kernel C: v = a@xt (MFMA) -> LN1 -> FFN (MFMA) -> LN2 ----------------
// 1 wave per block, 16 t-rows per block. 256 blocks = 4 b * 64 tiles.
__global__ __launch_bounds__(64) void tail_kernel(
    const float* __restrict__ a_f,
    const unsigned short* __restrict__ xbf,
    const float* __restrict__ x,
    const float* __restrict__ gamma1, const float* __restrict__ beta1,
    const unsigned short* __restrict__ w1bf, const float* __restrict__ b1,
    const unsigned short* __restrict__ w2bf, const float* __restrict__ b2,
    const float* __restrict__ gamma2, const float* __restrict__ beta2,
    float* __restrict__ y2out)
{
    __shared__ __attribute__((aligned(16))) unsigned short ysh[16 * 40];    // y bf16, padded stride 40
    __shared__ __attribute__((aligned(16))) unsigned short h1sh[16 * 136];  // h1 bf16, padded stride 136
    const int lane = threadIdx.x;
    const int col = lane & 15, g = lane >> 4;
    const int b = blockIdx.x >> 6;
    const int t0 = (blockIdx.x & 63) << 4;

    // --- v[t][c] = sum_j a[t][j] * x[b][c][j], MFMA 16x16x32, N=32 as 2 n-tiles ---
    v4f acc0 = {0.f, 0.f, 0.f, 0.f}, acc1 = {0.f, 0.f, 0.f, 0.f};
    {
        const float* arf = a_f + (((size_t)((b << 10) + t0 + col)) << 10) + (g << 3);
        const unsigned short* xr0 = xbf + (((size_t)((b << 5) + col)) << 10) + (g << 3);
        const unsigned short* xr1 = xr0 + (16 << 10);
        #pragma unroll 4
        for (int it = 0; it < 32; ++it) {
            float4 a4a = *(const float4*)(arf + (it << 5));
            float4 a4b = *(const float4*)(arf + (it << 5) + 4);
            v8s af;
            af[0] = (short)f2bf(a4a.x); af[1] = (short)f2bf(a4a.y);
            af[2] = (short)f2bf(a4a.z); af[3] = (short)f2bf(a4a.w);
            af[4] = (short)f2bf(a4b.x); af[5] = (short)f2bf(a4b.y);
            af[6] = (short)f2bf(a4b.z); af[7] = (short)f2bf(a4b.w);
            v8s bf0 = *(const v8s*)(xr0 + (it << 5));
            v8s bf1 = *(const v8s*)(xr1 + (it << 5));
            acc0 = __builtin_amdgcn_mfma_f32_16x16x32_bf16(af, bf0, acc0, 0, 0, 0);
            acc1 = __builtin_amdgcn_mfma_f32_16x16x32_bf16(af, bf1, acc1, 0, 0, 0);
        }
    }

    // --- y = LN1(x + v): lane holds (row = g*4+r, c = col / col+16) ---
    float y0[4], y1[4];
    {
        const float* xb = x + (size_t)b * (NC * NT);
        float g1a = gamma1[col], be1a = beta1[col];
        float g1b = gamma1[col + 16], be1b = beta1[col + 16];
        #pragma unroll
        for (int r = 0; r < 4; ++r) {
            int t = t0 + (g << 2) + r;
            float v0 = acc0[r] + xb[col * NT + t];
            float v1 = acc1[r] + xb[(col + 16) * NT + t];
            float s = v0 + v1, ss = v0 * v0 + v1 * v1;
            #pragma unroll
            for (int msk = 1; msk < 16; msk <<= 1) {   // reduce over the 16 lanes sharing g
                s  += __shfl_xor(s, msk);
                ss += __shfl_xor(ss, msk);
            }
            float mean = s * 0.03125f;
            float var = fmaf(-mean, mean, ss * 0.03125f) + 1e-14f;
            float rs = rsqrtf(var);
            y0[r] = (v0 - mean) * rs * g1a + be1a;
            y1[r] = (v1 - mean) * rs * g1b + be1b;
            int rowl = (g << 2) + r;
            ysh[rowl * 40 + col]      = f2bf(y0[r]);
            ysh[rowl * 40 + col + 16] = f2bf(y1[r]);
        }
    }
    __syncthreads();

    // --- h1 = relu(y @ W1^T + b1): K=32 (one MFMA k-step), 8 n-tiles of h ---
    v4f h1acc[8];
    #pragma unroll
    for (int nt = 0; nt < 8; ++nt) h1acc[nt] = (v4f){0.f, 0.f, 0.f, 0.f};
    {
        v8s ya = *(const v8s*)(ysh + col * 40 + (g << 3));   // A-frag: m=col, k=g*8+j
        #pragma unroll
        for (int nt = 0; nt < 8; ++nt) {
            v8s wb = *(const v8s*)(w1bf + ((nt << 4) + col) * NC + (g << 3)); // B[k=c][n=h]=W1[h][c]
            h1acc[nt] = __builtin_amdgcn_mfma_f32_16x16x32_bf16(ya, wb, h1acc[nt], 0, 0, 0);
        }
    }
    #pragma unroll
    for (int nt = 0; nt < 8; ++nt) {
        float bb = b1[(nt << 4) + col];
        #pragma unroll
        for (int r = 0; r < 4; ++r) {
            float hv = fmaxf(h1acc[nt][r] + bb, 0.f);
            h1sh[((g << 2) + r) * 136 + (nt << 4) + col] = f2bf(hv);
        }
    }
    __syncthreads();

    // --- h2 = h1 @ W2^T + b2: K=128 (4 k-steps), 2 n-tiles of c ---
    v4f ha0 = {0.f, 0.f, 0.f, 0.f}, ha1 = {0.f, 0.f, 0.f, 0.f};
    #pragma unroll
    for (int kb2 = 0; kb2 < 4; ++kb2) {
        v8s ha  = *(const v8s*)(h1sh + col * 136 + (kb2 << 5) + (g << 3));
        v8s w0  = *(const v8s*)(w2bf + col * NH + (kb2 << 5) + (g << 3));         // B[k=h][n=c]=W2[c][h]
        v8s w1v = *(const v8s*)(w2bf + (col + 16) * NH + (kb2 << 5) + (g << 3));
        ha0 = __builtin_amdgcn_mfma_f32_16x16x32_bf16(ha, w0, ha0, 0, 0, 0);
        ha1 = __builtin_amdgcn_mfma_f32_16x16x32_bf16(ha, w1v, ha1, 0, 0, 0);
    }

    // --- y2 = LN2(y + ff), store f32 to d_out[b][c][t] ---
    {
        float g2a = gamma2[col], be2a = beta2[col];
        float g2b = gamma2[col + 16], be2b = beta2[col + 16];
        float bb0 = b2[col], bb1 = b2[col + 16];
        float* yo = y2out + (size_t)b * (NC * NT);
        #pragma unroll
        for (int r = 0; r < 4; ++r) {
            float z0 = y0[r] + ha0[r] + bb0;
            float z1 = y1[r] + ha1[r] + bb1;
            float s = z0 + z1, ss = z0 * z0 + z1 * z1;
            #pragma unroll
            for (int msk = 1; msk < 16; msk <<= 1) {
                s  += __shfl_xor(s, msk);
                ss += __shfl_xor(ss, msk);
            }
            float mean = s * 0.03125f;
            float var = fmaf(-mean, mean, ss * 0.03125f) + 1e-14f;
            float rs = rsqrtf(var);
            int t = t0 + (g << 2) + r;
            yo[col * NT + t]        = (z0 - mean) * rs * g2a + be2a;
            yo[(col + 16) * NT + t] = (z1 - mean) * rs * g2b + be2b;
        }
    }
}

extern "C" void kernel_launch(void* const* d_in, const int* in_sizes, int n_in,
                              void* d_out, int out_size, void* d_ws, size_t ws_size,
                              hipStream_t stream)
{
    const float* x      = (const float*)d_in[0];
    const float* Wt     = (const float*)d_in[1];
    const float* Wx     = (const float*)d_in[2];
    const float* bh     = (const float*)d_in[3];
    const float* Wa     = (const float*)d_in[4];
    const float* ba     = (const float*)d_in[5];
    const float* gamma1 = (const float*)d_in[6];
    const float* beta1  = (const float*)d_in[7];
    const float* W1     = (const float*)d_in[8];
    const float* b1     = (const float*)d_in[9];
    const float* W2     = (const float*)d_in[10];
    const float* b2     = (const float*)d_in[11];
    const float* gamma2 = (const float*)d_in[12];
    const float* beta2  = (const float*)d_in[13];

    char* ws = (char*)d_ws;
    float* qb            = (float*)(ws);                    // 4096*32 f32  = 512 KB
    float* kx            = (float*)(ws + 524288);           // 4096*32 f32  = 512 KB
    unsigned short* xbf  = (unsigned short*)(ws + 1048576); // 131072 bf16  = 256 KB
    unsigned short* w1bf = (unsigned short*)(ws + 1310720); // 4096 bf16    = 8 KB
    unsigned short* w2bf = (unsigned short*)(ws + 1318912); // 4096 bf16    = 8 KB

    float* out = (float*)d_out;
    float* y2o = out;            // B*C*T = 131072 f32
    float* a_o = out + 131072;   // B*T*T = 4194304 f32

    prep_kernel<<<644, 256, 0, stream>>>(x, Wt, Wx, bh, W1, W2, qb, kx, xbf, w1bf, w2bf);
    attn_kernel<<<512, 256, 0, stream>>>(qb, kx, Wa, ba, a_o);
    tail_kernel<<<256, 64, 0, stream>>>(a_o, xbf, x, gamma1, beta1, w1bf, b1,
                                        w2bf, b2, gamma2, beta2, y2o);
}

// Round 3
// 115.571 us; speedup vs baseline: 1.1583x; 1.1583x over previous
//
#include <hip/hip_runtime.h>
#include <hip/hip_bf16.h>

typedef short v8s __attribute__((ext_vector_type(8)));
typedef float v4f __attribute__((ext_vector_type(4)));
typedef float v2f __attribute__((ext_vector_type(2)));

#define NB 4
#define NC 32
#define NT 1024
#define NU 32
#define NH 128

static __device__ __forceinline__ unsigned short f2bf(float f) {
    unsigned int u = __float_as_uint(f);
    return (unsigned short)((u + 0x7fffu + ((u >> 16) & 1u)) >> 16);  // RNE
}

static __device__ __forceinline__ v2f pkfma(v2f a, v2f b, v2f c) {
    return __builtin_elementwise_fma(a, b, c);   // -> v_pk_fma_f32
}

// ---------------- Kernel A: q/k projections + bf16 copies ----------------
__global__ __launch_bounds__(256) void prep_kernel(
    const float* __restrict__ x, const float* __restrict__ Wt,
    const float* __restrict__ Wx, const float* __restrict__ bh,
    const float* __restrict__ W1, const float* __restrict__ W2,
    float* __restrict__ qb, float* __restrict__ kx,
    unsigned short* __restrict__ xbf,
    unsigned short* __restrict__ w1bf, unsigned short* __restrict__ w2bf)
{
    int bid = blockIdx.x, tid = threadIdx.x;
    if (bid < 512) {
        int gid = (bid << 8) + tid;
        int row = gid >> 5, u = gid & 31;        // row = b*1024 + t
        int b = row >> 10, t = row & 1023;
        const float* xp = x + (size_t)b * (NC * NT) + t;
        float aq = 0.f, ak = 0.f;
        #pragma unroll
        for (int c = 0; c < NC; ++c) {
            float xv = xp[c * NT];
            aq = fmaf(xv, Wt[c * NU + u], aq);
            ak = fmaf(xv, Wx[c * NU + u], ak);
        }
        qb[(size_t)row * NU + u] = aq + bh[u];   // q + bh folded
        kx[(size_t)row * NU + u] = ak;
    } else if (bid < 640) {                      // x -> bf16, same [b][c][t] layout
        int base = ((bid - 512) << 10) + (tid << 2);
        float4 xv = *(const float4*)(x + base);
        xbf[base]     = f2bf(xv.x);
        xbf[base + 1] = f2bf(xv.y);
        xbf[base + 2] = f2bf(xv.z);
        xbf[base + 3] = f2bf(xv.w);
    } else if (bid < 642) {                      // W1 (128x32) -> bf16
        int base = ((bid - 640) << 11) + (tid << 3);
        #pragma unroll
        for (int i = 0; i < 8; ++i) w1bf[base + i] = f2bf(W1[base + i]);
    } else {                                     // W2 (32x128) -> bf16
        int base = ((bid - 642) << 11) + (tid << 3);
        #pragma unroll
        for (int i = 0; i < 8; ++i) w2bf[base + i] = f2bf(W2[base + i]);
    }
}

// ---------------- Kernel B: e = Wa . tanh(q+k+bh) + ba, softmax ----------------
// Block = 256 threads (4 waves), handles 8 rows. k[b] staged in LDS in two
// 512-row phases (64 KB, XOR-swizzled 16B chunks -> conflict-free ds_read_b128).
// Packed-f32 (v_pk_fma) degree-5 tanh. Writes a as f32 (d_out) + bf16 (ws).
__global__ __launch_bounds__(256) void attn_kernel(
    const float* __restrict__ qb, const float* __restrict__ kx,
    const float* __restrict__ Wa, const float* __restrict__ ba,
    float* __restrict__ a_out, unsigned short* __restrict__ abf)
{
    __shared__ __attribute__((aligned(16))) float klds[512 * 32];  // 64 KB
    const int tid = threadIdx.x;
    const int lane = tid & 63;
    const int wv = tid >> 6;
    const int row0 = (blockIdx.x << 3) + (wv << 1);
    const int b = row0 >> 10;

    v2f wa2[16];
    #pragma unroll
    for (int p = 0; p < 16; ++p) wa2[p] = (v2f){Wa[2 * p], Wa[2 * p + 1]};
    const float bav = ba[0];

    v2f q0[16], q1[16];
    {
        const float* qp = qb + (size_t)row0 * NU;
        #pragma unroll
        for (int u = 0; u < NU; u += 4) {
            float4 t4 = *(const float4*)(qp + u);
            q0[u >> 1] = (v2f){t4.x, t4.y};
            q0[(u >> 1) + 1] = (v2f){t4.z, t4.w};
        }
        #pragma unroll
        for (int u = 0; u < NU; u += 4) {
            float4 t4 = *(const float4*)(qp + NU + u);
            q1[u >> 1] = (v2f){t4.x, t4.y};
            q1[(u >> 1) + 1] = (v2f){t4.z, t4.w};
        }
    }

    // tanh(z) ~= z + z*z2*(C1 + C2*z2), |z| <~ 0.5 here (deg-5, err<4e-4 worst)
    const v2f C1v = {-0.33333334f, -0.33333334f};
    const v2f C2v = {0.13333334f, 0.13333334f};

    float e0[16], e1[16];
    #pragma unroll 1
    for (int ph = 0; ph < 2; ++ph) {
        __syncthreads();
        // stage 512 rows x 32 f32 of k[b] into LDS, swizzled: chunk c of row j
        // lands at j*32 + ((c ^ (j&7))*4)
        {
            const float* src = kx + ((size_t)b << 15) + (ph << 14);
            #pragma unroll
            for (int i = 0; i < 16; ++i) {
                int flat = (i << 8) + tid;          // (row j)*8 + chunk c
                int j = flat >> 3, c = flat & 7;
                float4 v = *(const float4*)(src + (flat << 2));
                *(float4*)(klds + (j << 5) + ((c ^ (j & 7)) << 2)) = v;
            }
        }
        __syncthreads();

        #pragma unroll
        for (int mm = 0; mm < 8; ++mm) {
            const int jl = (mm << 6) + lane;
            const float* kp = klds + (jl << 5);
            const int sw = jl & 7;
            v2f kr[16];
            #pragma unroll
            for (int c = 0; c < 8; ++c) {
                float4 t4 = *(const float4*)(kp + ((c ^ sw) << 2));
                kr[2 * c] = (v2f){t4.x, t4.y};
                kr[2 * c + 1] = (v2f){t4.z, t4.w};
            }
            v2f acc0 = {0.f, 0.f}, acc1 = {0.f, 0.f};
            #pragma unroll
            for (int p = 0; p < 16; ++p) {
                v2f k2 = kr[p];
                v2f z0 = q0[p] + k2;
                v2f z1 = q1[p] + k2;
                v2f s0 = z0 * z0, s1 = z1 * z1;
                v2f w0 = pkfma(s0, C2v, C1v);
                v2f w1 = pkfma(s1, C2v, C1v);
                v2f zs0 = z0 * s0, zs1 = z1 * s1;
                v2f t0 = pkfma(zs0, w0, z0);
                v2f t1 = pkfma(zs1, w1, z1);
                acc0 = pkfma(wa2[p], t0, acc0);
                acc1 = pkfma(wa2[p], t1, acc1);
            }
            e0[(ph << 3) + mm] = acc0[0] + acc0[1] + bav;
            e1[(ph << 3) + mm] = acc1[0] + acc1[1] + bav;
        }
    }

    // exact reference semantics: shift by row max, denom = sum + 1e-5
    float mx0 = e0[0], mx1 = e1[0];
    #pragma unroll
    for (int m = 1; m < 16; ++m) { mx0 = fmaxf(mx0, e0[m]); mx1 = fmaxf(mx1, e1[m]); }
    #pragma unroll
    for (int o = 32; o; o >>= 1) {
        mx0 = fmaxf(mx0, __shfl_xor(mx0, o));
        mx1 = fmaxf(mx1, __shfl_xor(mx1, o));
    }
    float S0 = 0.f, S1 = 0.f;
    float s0a[16], s1a[16];
    #pragma unroll
    for (int m = 0; m < 16; ++m) {
        s0a[m] = __expf(e0[m] - mx0); S0 += s0a[m];
        s1a[m] = __expf(e1[m] - mx1); S1 += s1a[m];
    }
    #pragma unroll
    for (int o = 32; o; o >>= 1) { S0 += __shfl_xor(S0, o); S1 += __shfl_xor(S1, o); }
    float i0 = 1.f / (S0 + 1e-5f);
    float i1 = 1.f / (S1 + 1e-5f);

    float* a0p = a_out + ((size_t)row0 << 10) + lane;
    unsigned short* b0p = abf + ((size_t)row0 << 10) + lane;
    #pragma unroll
    for (int m = 0; m < 16; ++m) {
        float va = s0a[m] * i0;
        float vb = s1a[m] * i1;
        a0p[(m << 6)]      = va;
        a0p[NT + (m << 6)] = vb;
        b0p[(m << 6)]      = f2bf(va);
        b0p[NT + (m << 6)] = f2bf(vb);
    }
}

// ---------------- Kernel C: v = a@xt (MFMA, 4-wave K-split) -> LN1 -> FFN -> LN2 ----
// Block = 256 threads (4 waves), one 16-row tile. 256 blocks = 4 b * 64 tiles.
__global__ __launch_bounds__(256) void tail_kernel(
    const unsigned short* __restrict__ abf,
    const unsigned short* __restrict__ xbf,
    const float* __restrict__ x,
    const float* __restrict__ gamma1, const float* __restrict__ beta1,
    const unsigned short* __restrict__ w1bf, const float* __restrict__ b1,
    const unsigned short* __restrict__ w2bf, const float* __restrict__ b2,
    const float* __restrict__ gamma2, const float* __restrict__ beta2,
    float* __restrict__ y2out)
{
    __shared__ __attribute__((aligned(16))) float red[4 * 64 * 9];          // padded, 9.2 KB
    __shared__ __attribute__((aligned(16))) unsigned short ysh[16 * 40];    // y bf16
    __shared__ __attribute__((aligned(16))) unsigned short h1sh[16 * 136];  // h1 bf16
    const int tid = threadIdx.x;
    const int lane = tid & 63;
    const int wv = tid >> 6;
    const int col = lane & 15, g = lane >> 4;
    const int b = blockIdx.x >> 6;
    const int t0 = (blockIdx.x & 63) << 4;

    // --- v partial: wave wv covers K-chunks [wv*8, wv*8+8) of 32 ---
    v4f acc0 = {0.f, 0.f, 0.f, 0.f}, acc1 = {0.f, 0.f, 0.f, 0.f};
    {
        const unsigned short* ar  = abf + (((size_t)((b << 10) + t0 + col)) << 10) + (g << 3);
        const unsigned short* xr0 = xbf + (((size_t)((b << 5) + col)) << 10) + (g << 3);
        const unsigned short* xr1 = xr0 + (16 << 10);
        const int it0 = wv << 3;
        #pragma unroll
        for (int i = 0; i < 8; ++i) {
            int it = it0 + i;
            v8s af  = *(const v8s*)(ar  + (it << 5));
            v8s bf0 = *(const v8s*)(xr0 + (it << 5));
            v8s bf1 = *(const v8s*)(xr1 + (it << 5));
            acc0 = __builtin_amdgcn_mfma_f32_16x16x32_bf16(af, bf0, acc0, 0, 0, 0);
            acc1 = __builtin_amdgcn_mfma_f32_16x16x32_bf16(af, bf1, acc1, 0, 0, 0);
        }
    }
    {
        float* rp = red + ((wv << 6) + lane) * 9;
        #pragma unroll
        for (int r = 0; r < 4; ++r) { rp[r] = acc0[r]; rp[4 + r] = acc1[r]; }
    }
    __syncthreads();

    float y0[4], y1[4];
    if (wv == 0) {
        #pragma unroll
        for (int w = 1; w < 4; ++w) {
            const float* rp = red + ((w << 6) + lane) * 9;
            #pragma unroll
            for (int r = 0; r < 4; ++r) { acc0[r] += rp[r]; acc1[r] += rp[4 + r]; }
        }
        // --- y = LN1(x + v): lane holds (row = g*4+r, c = col / col+16) ---
        const float* xb = x + (size_t)b * (NC * NT);
        float g1a = gamma1[col], be1a = beta1[col];
        float g1b = gamma1[col + 16], be1b = beta1[col + 16];
        #pragma unroll
        for (int r = 0; r < 4; ++r) {
            int t = t0 + (g << 2) + r;
            float v0 = acc0[r] + xb[col * NT + t];
            float v1 = acc1[r] + xb[(col + 16) * NT + t];
            float s = v0 + v1, ss = v0 * v0 + v1 * v1;
            #pragma unroll
            for (int msk = 1; msk < 16; msk <<= 1) {
                s  += __shfl_xor(s, msk);
                ss += __shfl_xor(ss, msk);
            }
            float mean = s * 0.03125f;
            float var = fmaf(-mean, mean, ss * 0.03125f) + 1e-14f;
            float rs = rsqrtf(var);
            y0[r] = (v0 - mean) * rs * g1a + be1a;
            y1[r] = (v1 - mean) * rs * g1b + be1b;
            int rowl = (g << 2) + r;
            ysh[rowl * 40 + col]      = f2bf(y0[r]);
            ysh[rowl * 40 + col + 16] = f2bf(y1[r]);
        }
    }
    __syncthreads();

    v4f h1acc[8];
    if (wv == 0) {
        // --- h1 = relu(y @ W1^T + b1): K=32, 8 n-tiles ---
        #pragma unroll
        for (int nt = 0; nt < 8; ++nt) h1acc[nt] = (v4f){0.f, 0.f, 0.f, 0.f};
        v8s ya = *(const v8s*)(ysh + col * 40 + (g << 3));   // A-frag: m=col, k=g*8+j
        #pragma unroll
        for (int nt = 0; nt < 8; ++nt) {
            v8s wb = *(const v8s*)(w1bf + ((nt << 4) + col) * NC + (g << 3));
            h1acc[nt] = __builtin_amdgcn_mfma_f32_16x16x32_bf16(ya, wb, h1acc[nt], 0, 0, 0);
        }
        #pragma unroll
        for (int nt = 0; nt < 8; ++nt) {
            float bb = b1[(nt << 4) + col];
            #pragma unroll
            for (int r = 0; r < 4; ++r) {
                float hv = fmaxf(h1acc[nt][r] + bb, 0.f);
                h1sh[((g << 2) + r) * 136 + (nt << 4) + col] = f2bf(hv);
            }
        }
    }
    __syncthreads();

    if (wv == 0) {
        // --- h2 = h1 @ W2^T + b2: K=128 (4 k-steps), 2 n-tiles ---
        v4f ha0 = {0.f, 0.f, 0.f, 0.f}, ha1 = {0.f, 0.f, 0.f, 0.f};
        #pragma unroll
        for (int kb2 = 0; kb2 < 4; ++kb2) {
            v8s ha  = *(const v8s*)(h1sh + col * 136 + (kb2 << 5) + (g << 3));
            v8s w0  = *(const v8s*)(w2bf + col * NH + (kb2 << 5) + (g << 3));
            v8s w1v = *(const v8s*)(w2bf + (col + 16) * NH + (kb2 << 5) + (g << 3));
            ha0 = __builtin_amdgcn_mfma_f32_16x16x32_bf16(ha, w0, ha0, 0, 0, 0);
            ha1 = __builtin_amdgcn_mfma_f32_16x16x32_bf16(ha, w1v, ha1, 0, 0, 0);
        }
        // --- y2 = LN2(y + ff), store f32 ---
        float g2a = gamma2[col], be2a = beta2[col];
        float g2b = gamma2[col + 16], be2b = beta2[col + 16];
        float bb0 = b2[col], bb1 = b2[col + 16];
        float* yo = y2out + (size_t)b * (NC * NT);
        #pragma unroll
        for (int r = 0; r < 4; ++r) {
            float z0 = y0[r] + ha0[r] + bb0;
            float z1 = y1[r] + ha1[r] + bb1;
            float s = z0 + z1, ss = z0 * z0 + z1 * z1;
            #pragma unroll
            for (int msk = 1; msk < 16; msk <<= 1) {
                s  += __shfl_xor(s, msk);
                ss += __shfl_xor(ss, msk);
            }
            float mean = s * 0.03125f;
            float var = fmaf(-mean, mean, ss * 0.03125f) + 1e-14f;
            float rs = rsqrtf(var);
            int t = t0 + (g << 2) + r;
            yo[col * NT + t]        = (z0 - mean) * rs * g2a + be2a;
            yo[(col + 16) * NT + t] = (z1 - mean) * rs * g2b + be2b;
        }
    }
}

extern "C" void kernel_launch(void* const* d_in, const int* in_sizes, int n_in,
                              void* d_out, int out_size, void* d_ws, size_t ws_size,
                              hipStream_t stream)
{
    const float* x      = (const float*)d_in[0];
    const float* Wt     = (const float*)d_in[1];
    const float* Wx     = (const float*)d_in[2];
    const float* bh     = (const float*)d_in[3];
    const float* Wa     = (const float*)d_in[4];
    const float* ba     = (const float*)d_in[5];
    const float* gamma1 = (const float*)d_in[6];
    const float* beta1  = (const float*)d_in[7];
    const float* W1     = (const float*)d_in[8];
    const float* b1     = (const float*)d_in[9];
    const float* W2     = (const float*)d_in[10];
    const float* b2     = (const float*)d_in[11];
    const float* gamma2 = (const float*)d_in[12];
    const float* beta2  = (const float*)d_in[13];

    char* ws = (char*)d_ws;
    float* qb            = (float*)(ws);                    // 512 KB
    float* kx            = (float*)(ws + 524288);           // 512 KB
    unsigned short* xbf  = (unsigned short*)(ws + 1048576); // 256 KB
    unsigned short* w1bf = (unsigned short*)(ws + 1310720); // 8 KB
    unsigned short* w2bf = (unsigned short*)(ws + 1318912); // 8 KB
    unsigned short* abf  = (unsigned short*)(ws + 1327104); // 8 MB

    float* out = (float*)d_out;
    float* y2o = out;            // B*C*T = 131072 f32
    float* a_o = out + 131072;   // B*T*T = 4194304 f32

    prep_kernel<<<644, 256, 0, stream>>>(x, Wt, Wx, bh, W1, W2, qb, kx, xbf, w1bf, w2bf);
    attn_kernel<<<512, 256, 0, stream>>>(qb, kx, Wa, ba, a_o, abf);
    tail_kernel<<<256, 256, 0, stream>>>(abf, xbf, x, gamma1, beta1, w1bf, b1,
                                         w2bf, b2, gamma2, beta2, y2o);
}